// Round 6
// baseline (185.572 us; speedup 1.0000x reference)
//
#include <hip/hip_runtime.h>

#define NN 400
#define HID 96
#define EDGES 79800
#define BATCH 16
#define ROWS (BATCH*EDGES)
#define NT 13            // node tiles of 32 (tile 12 half-padded)
#define NPAIRS 91        // NT*(NT+1)/2

typedef _Float16 f16;
typedef f16 f16x2 __attribute__((ext_vector_type(2)));
typedef f16 f16x8 __attribute__((ext_vector_type(8)));
typedef __fp16 fp16x2 __attribute__((ext_vector_type(2)));
typedef float f32x16 __attribute__((ext_vector_type(16)));
typedef unsigned int u32;
typedef unsigned long long u64;

union H8 { f16x8 h; u32 u[4]; f16x2 p[4]; fp16x2 q[4]; u64 d[2]; };
union C2 { f16x2 h; fp16x2 q; u32 u; };

__device__ inline f16x2 pkrtz(float a, float b) {
  C2 c; c.q = __builtin_amdgcn_cvt_pkrtz(a, b); return c.h;
}
__device__ inline u32 pkrtz_u(float a, float b) {
  C2 c; c.q = __builtin_amdgcn_cvt_pkrtz(a, b); return c.u;
}
__device__ inline float fdot2a(f16x2 a, f16x2 b, float c) {
#if __has_builtin(__builtin_amdgcn_fdot2)
  C2 ca, cb; ca.h = a; cb.h = b;
  return __builtin_amdgcn_fdot2(ca.q, cb.q, c, false);
#else
  return c + (float)a.x*(float)b.x + (float)a.y*(float)b.y;
#endif
}

__device__ inline f16x8 habs8(f16x8 x) {
  H8 t; t.h = x;
  t.u[0] &= 0x7fff7fffu; t.u[1] &= 0x7fff7fffu;
  t.u[2] &= 0x7fff7fffu; t.u[3] &= 0x7fff7fffu;
  return t.h;
}

__device__ inline f16x8 pack8(float a0,float a1,float a2,float a3,
                              float a4,float a5,float a6,float a7){
  H8 u;
  u.p[0] = pkrtz(a0,a1);
  u.p[1] = pkrtz(a2,a3);
  u.p[2] = pkrtz(a4,a5);
  u.p[3] = pkrtz(a6,a7);
  return u.h;
}

// v_permlane32_swap_b32: vdst.hi32lanes <-> vsrc.lo32lanes.
__device__ inline void plswap(u32 &x, u32 &y) {
  auto r = __builtin_amdgcn_permlane32_swap((int)x, (int)y, false, false);
  x = (u32)r[0]; y = (u32)r[1];
}

// Aliasing fence: stops LICM/scheduler from hoisting+clustering loop-invariant LDS reads
// (the R2-R4 spill source). Register-only ops (MFMA, packs) are unaffected.
#define MEMFENCE asm volatile("" ::: "memory")

// ---------------- fused prep (blocks 0..139) + per-batch partial mean (blocks 140..395) --------
// wq regions (dwords): Wd1 [0,9216)  Wd2 plain-K [9216,11264)  We1 [11264,31232)  We2 [31232,35840)
__global__ void prep_mean_kernel(const float* __restrict__ We1, const float* __restrict__ We2,
                                 const float* __restrict__ W1, const float* __restrict__ W2,
                                 const float* __restrict__ sc,
                                 u32* __restrict__ wq, float* __restrict__ mpart) {
  if (blockIdx.x >= 140) {
    int p = blockIdx.x - 140;           // 0..255
    int b = p >> 4, part = p & 15;
    const float4* src = (const float4*)(sc + (size_t)b*160000) + part*2500;
    float s = 0.f;
    for (int i = threadIdx.x; i < 2500; i += 256) {
      float4 v = src[i];
      s += (v.x + v.y) + (v.z + v.w);
    }
    __shared__ float red[256];
    red[threadIdx.x] = s; __syncthreads();
    for (int off = 128; off > 0; off >>= 1) {
      if (threadIdx.x < off) red[threadIdx.x] += red[threadIdx.x + off];
      __syncthreads();
    }
    if (threadIdx.x == 0) mpart[p] = red[0];
    return;
  }
  int D = blockIdx.x*256 + threadIdx.x;     // 0..35839
  float v0, v1;
  if (D < 9216) {               // W_d1 frags (288 x 64), d = 32q+c  (A-frag == B-frag layout)
    int frag = D >> 8;  int t = frag >> 1, q = frag & 1;
    int rem = D & 255;  int lane = rem >> 2, dj = rem & 3;
    int c = lane & 31, h2 = lane >> 5;
    int k = 16*t + 8*h2 + 2*dj;
    int d = 32*q + c;
    v0 = W1[k*64 + d]; v1 = W1[(k+1)*64 + d];
  } else if (D < 11264) {       // W_d2 frags, PLAIN K (A-frags for swapped layer-2)
    int Dl = D - 9216;
    int frag = Dl >> 8; int t2 = frag >> 1, q = frag & 1;
    int rem = Dl & 255; int lane = rem >> 2, dj = rem & 3;
    int c = lane & 31, h2 = lane >> 5;
    int k = 16*t2 + 8*h2 + 2*dj;
    int d = 32*q + c;
    v0 = W2[k*64 + d]; v1 = W2[(k+1)*64 + d];
  } else if (D < 31232) {       // W_e1 frags (416 x 96), sc features first, static at 400
    int Dl = D - 11264;
    int frag = Dl >> 8; int t = frag/3, ct = frag - 3*t;
    int rem = Dl & 255; int lane = rem >> 2, dj = rem & 3;
    int c = lane & 31, h2 = lane >> 5;
    int k0 = 16*t + 8*h2 + 2*dj, k1 = k0 + 1;
    int d = 32*ct + c;
    v0 = (k0 < 400) ? We1[(8+k0)*96 + d] : (k0 < 408 ? We1[(k0-400)*96 + d] : 0.f);
    v1 = (k1 < 400) ? We1[(8+k1)*96 + d] : (k1 < 408 ? We1[(k1-400)*96 + d] : 0.f);
  } else {                      // W_e2 frags (96 x 96), plain K order
    int Dl = D - 31232;
    int frag = Dl >> 8; int t = frag/3, ct = frag - 3*t;
    int rem = Dl & 255; int lane = rem >> 2, dj = rem & 3;
    int c = lane & 31, h2 = lane >> 5;
    int k = 16*t + 8*h2 + 2*dj;
    int d = 32*ct + c;
    v0 = We2[k*96 + d]; v1 = We2[(k+1)*96 + d];
  }
  wq[D] = pkrtz_u(v0, v1);
}

// ---------------- fused encoder, K-split across 4 waves (R6 form, measured best) ---------------
__global__ __launch_bounds__(256) void enc_kernel(
    const float* __restrict__ sc, const float* __restrict__ nf,
    const float* __restrict__ smean, const float* __restrict__ sstd,
    const float* __restrict__ be1, const float* __restrict__ ae1,
    const float* __restrict__ be2, const float* __restrict__ ae2,
    const float* __restrict__ mpart, const u32* __restrict__ wq,
    f16* __restrict__ hout) {
  __shared__ u32 lds[12288 + 1664];
  const int tid = threadIdx.x;
  const int wid = tid >> 6, lane = tid & 63;
  const int c = lane & 31, h2 = lane >> 5;
  const int r0 = blockIdx.x * 32;
  {
    int row = tid >> 3, seg = tid & 7;
    int r = r0 + row;
    int b = r / 400;
    float ms = 0.f;
    const float4* mp4 = (const float4*)(mpart + 16*b);
#pragma unroll
    for (int k = 0; k < 4; ++k) { float4 v = mp4[k]; ms += (v.x+v.y)+(v.z+v.w); }
    float rm = 1.f / fmaxf(ms*(1.f/160000.f), 1e-8f);
    const float4* src = (const float4*)(sc + (size_t)r*400);
#pragma unroll
    for (int i = 0; i < 13; ++i) {
      int col4 = seg + 8*i;
      if (col4 < 100) {
        float4 v = src[col4];
        u32 lo = pkrtz_u(v.x*rm, v.y*rm);
        u32 hi = pkrtz_u(v.z*rm, v.w*rm);
        *(u64*)(lds + row*210 + col4*2) = (u64)lo | ((u64)hi << 32);
      }
    }
  }
  __syncthreads();
  int tb = (wid==0) ? 0 : (wid==1) ? 7 : (wid==2) ? 14 : 20;
  int te = (wid==0) ? 7 : (wid==1) ? 14 : (wid==2) ? 20 : 26;
  f32x16 acc[3] = {};
  const u32* wb1 = wq + 11264;
  for (int t = tb; t < te; ++t) {
    f16x8 af;
    if (t < 25) {
      H8 av;
      const u32* ap = lds + c*210 + 8*t + 4*h2;
      av.d[0] = *(const u64*)ap;
      av.d[1] = *(const u64*)(ap + 2);
      af = av.h;
    } else {
      af = (f16x8){};
      if (h2 == 0) {
        int r = r0 + c;
        float q0[8];
#pragma unroll
        for (int j = 0; j < 8; ++j)
          q0[j] = (nf[r*8 + j] - smean[j]) / (sstd[j] + 1e-8f);
        af = pack8(q0[0],q0[1],q0[2],q0[3],q0[4],q0[5],q0[6],q0[7]);
      }
    }
#pragma unroll
    for (int ct = 0; ct < 3; ++ct) {
      f16x8 bf = *(const f16x8*)(wb1 + ((t*3+ct)*64 + lane)*4);
      acc[ct] = __builtin_amdgcn_mfma_f32_32x32x16_f16(af, bf, acc[ct], 0,0,0);
    }
  }
  __syncthreads();
#pragma unroll
  for (int ct = 0; ct < 3; ++ct) {
    union { f32x16 v; float4 f[4]; } u; u.v = acc[ct];
#pragma unroll
    for (int i4 = 0; i4 < 4; ++i4)
      *(float4*)(lds + (((wid*3+ct)*4 + i4)*64 + lane)*4) = u.f[i4];
  }
  __syncthreads();
  f16* zb16 = (f16*)(lds + 12288);
  const float a1 = *ae1;
  if (wid < 3) {
    float bv = be1[32*wid + c];
    f32x16 s;
#pragma unroll
    for (int i = 0; i < 16; ++i) s[i] = bv;
#pragma unroll
    for (int w2 = 0; w2 < 4; ++w2) {
#pragma unroll
      for (int i4 = 0; i4 < 4; ++i4) {
        float4 f = *(const float4*)(lds + (((w2*3+wid)*4 + i4)*64 + lane)*4);
        s[4*i4+0] += f.x; s[4*i4+1] += f.y; s[4*i4+2] += f.z; s[4*i4+3] += f.w;
      }
    }
#pragma unroll
    for (int r = 0; r < 16; ++r) {
      float v = s[r]; v = fmaxf(v, a1*v);
      int row = (r & 3) + 8*(r >> 2) + 4*h2;
      zb16[row*104 + 32*wid + c] = (f16)v;
    }
  }
  __syncthreads();
  if (wid < 3) {
    const float a2 = *ae2;
    float bv = be2[32*wid + c];
    f32x16 acc2;
#pragma unroll
    for (int i = 0; i < 16; ++i) acc2[i] = bv;
    const u32* wb2 = wq + 31232;
#pragma unroll
    for (int t = 0; t < 6; ++t) {
      f16x8 af = *(const f16x8*)(zb16 + c*104 + 16*t + 8*h2);
      f16x8 bf = *(const f16x8*)(wb2 + ((t*3+wid)*64 + lane)*4);
      acc2 = __builtin_amdgcn_mfma_f32_32x32x16_f16(af, bf, acc2, 0,0,0);
    }
#pragma unroll
    for (int rr = 0; rr < 16; ++rr) {
      int row = (rr & 3) + 8*(rr >> 2) + 4*h2;
      float v = acc2[rr]; v = fmaxf(v, a2*v);
      hout[(r0 + row)*96 + 32*wid + c] = (f16)v;
    }
  }
}

// ---------------- decoder v7: v6 (fences, no-spill) at 3 blocks/CU ----------------
// R5 proved fences cut true demand to 112 VGPRs — well under the (256,3) ~170 cap that
// spilled in R2/R3 against the ~320-reg HOISTED demand. LDS 3x51,200 = 153,600 <= 163,840.
// 3 blocks/CU = 3 waves/SIMD -> 50% more latency hiding for the LDS-latency-bound loop.
// LDS (dwords): hI [0,1536)  Wd1 frags [1536,10752)  Wd2 frags [10752,12800)  = 51,200 B
__global__ __launch_bounds__(256, 3) void decoder_kernel(
    const f16* __restrict__ hbuf, const u32* __restrict__ wq,
    const float* __restrict__ b1, const float* __restrict__ b2,
    const float* __restrict__ ad1, const float* __restrict__ ad2,
    const float* __restrict__ W3, const float* __restrict__ b3p,
    float* __restrict__ out) {
  __shared__ alignas(16) u32 smem[12800];
  const int tid = threadIdx.x;
  // task decode
  int p = blockIdx.x;
  int b = p / NPAIRS, pr = p - b*NPAIRS;
  int I = 0;
  while (pr >= NT - I) { pr -= NT - I; ++I; }
  const int J = I + pr;
  // stage hI rows: 32 rows x 48 dwords (clamped for tile 12)
  for (int i = tid; i < 384; i += 256) {
    int row = i / 12, off = i - row*12;
    int nb = I*32 + row; nb = nb < NN ? nb : NN-1;
    const float4* src = (const float4*)(hbuf + (size_t)(b*NN + nb)*HID) + off;
    *((float4*)(smem + row*48) + off) = *src;
  }
  // stage Wd1 (9216 dw) + Wd2 (2048 dw) contiguously
  {
    float4* dst = (float4*)(smem + 1536);
    const float4* srcw = (const float4*)wq;
    for (int i = tid; i < 2816; i += 256) dst[i] = srcw[i];
  }

  const int lane = tid & 63;
  const int wid  = tid >> 6;
  const int c = lane & 31, h2 = lane >> 5;
  const int gj = J*32 + c;
  const int gjc = gj < NN ? gj : NN-1;
  // hj frags for this lane's edge column, loop-invariant -> registers (from global, L2-hot)
  f16x8 hjr[6];
  {
    const f16* hjp = hbuf + (size_t)(b*NN + gjc)*HID + 8*h2;
#pragma unroll
    for (int t = 0; t < 6; ++t) hjr[t] = *(const f16x8*)(hjp + 16*t);
  }
  const float a1 = *ad1, a2 = *ad2, b3 = *b3p;
  const f16x2 a1v = pkrtz(a1, a1);
  const f16x2 a2v = pkrtz(a2, a2);
  // bias MFMA operands: B = const-1 frag (k-slot 0 of the extra kstep), A = bias column
  f16x8 bcst = (f16x8){};
  f16x8 ab1f[2]; ab1f[0] = (f16x8){}; ab1f[1] = (f16x8){};
  f16x8 ab2f[2]; ab2f[0] = (f16x8){}; ab2f[1] = (f16x8){};
  if (h2 == 0) {
    bcst[0] = (f16)1.f;
    ab1f[0][0] = (f16)b1[c];      ab1f[1][0] = (f16)b1[32 + c];
    ab2f[0][0] = (f16)b2[c];      ab2f[1][0] = (f16)b2[32 + c];
  }
  // W3 packed per-lane pairs matching acc row layout
  f16x2 w3q[2][8];
#pragma unroll
  for (int q2 = 0; q2 < 2; ++q2)
#pragma unroll
    for (int a = 0; a < 8; ++a) {
      int base = 32*q2 + 8*(a >> 1) + 2*(a & 1) + 4*h2;
      w3q[q2][a] = pkrtz(W3[base], W3[base + 1]);
    }
  __syncthreads();

  const f16* hIb = (const f16*)smem;
  const u32* wfr = smem + 1536;
  const u32* w2a = smem + 10752;
  const int bofs = b*EDGES;

#pragma unroll 1
  for (int it = 0; it < 4; ++it) {
    MEMFENCE;                                  // block LICM across the it-loop
    const int i0 = it*8 + wid*2;
    const f16* hi0 = hIb + (i0+0)*HID;
    const f16* hi1 = hIb + (i0+1)*HID;
    f32x16 acc[2][2] = {};
    // bias kstep first (off the critical path)
#pragma unroll
    for (int m = 0; m < 2; ++m) {
      acc[m][0] = __builtin_amdgcn_mfma_f32_32x32x16_f16(ab1f[0], bcst, acc[m][0], 0,0,0);
      acc[m][1] = __builtin_amdgcn_mfma_f32_32x32x16_f16(ab1f[1], bcst, acc[m][1], 0,0,0);
    }
    // layer 1: K=288 = 6 octet-steps x {sum, absdiff, prod}; A = W1^T frags from LDS
#pragma unroll
    for (int t = 0; t < 6; ++t) {
      MEMFENCE;                                // partition loads: <=6 weight frags live
      f16x8 as0 = *(const f16x8*)(wfr + (((t    )*2+0)*64 + lane)*4);
      f16x8 as1 = *(const f16x8*)(wfr + (((t    )*2+1)*64 + lane)*4);
      f16x8 ad0 = *(const f16x8*)(wfr + (((t+ 6)*2+0)*64 + lane)*4);
      f16x8 ad1_ = *(const f16x8*)(wfr + (((t+ 6)*2+1)*64 + lane)*4);
      f16x8 ap0 = *(const f16x8*)(wfr + (((t+12)*2+0)*64 + lane)*4);
      f16x8 ap1 = *(const f16x8*)(wfr + (((t+12)*2+1)*64 + lane)*4);
      f16x8 hj8 = hjr[t];
#pragma unroll
      for (int m = 0; m < 2; ++m) {
        f16x8 hi8 = *(const f16x8*)((m ? hi1 : hi0) + 16*t + 8*h2);   // broadcast read
        f16x8 su = hi8 + hj8;
        f16x8 di = habs8(hi8 - hj8);
        f16x8 prd = hi8 * hj8;
        acc[m][0] = __builtin_amdgcn_mfma_f32_32x32x16_f16(as0, su,  acc[m][0], 0,0,0);
        acc[m][1] = __builtin_amdgcn_mfma_f32_32x32x16_f16(as1, su,  acc[m][1], 0,0,0);
        acc[m][0] = __builtin_amdgcn_mfma_f32_32x32x16_f16(ad0, di,  acc[m][0], 0,0,0);
        acc[m][1] = __builtin_amdgcn_mfma_f32_32x32x16_f16(ad1_, di, acc[m][1], 0,0,0);
        acc[m][0] = __builtin_amdgcn_mfma_f32_32x32x16_f16(ap0, prd, acc[m][0], 0,0,0);
        acc[m][1] = __builtin_amdgcn_mfma_f32_32x32x16_f16(ap1, prd, acc[m][1], 0,0,0);
      }
    }
#pragma unroll
    for (int m = 0; m < 2; ++m) {
      // pack + packed-prelu the 32 z1 values, then permlane-swap h2 halves -> layer-2 B-frags
      u32 w[16];
#pragma unroll
      for (int q = 0; q < 2; ++q)
#pragma unroll
        for (int a = 0; a < 8; ++a) {
          f16x2 pz = pkrtz(acc[m][q][2*a], acc[m][q][2*a+1]);
          pz = __builtin_elementwise_max(pz, pz * a1v);
          C2 cv; cv.h = pz; w[q*8 + a] = cv.u;
        }
#pragma unroll
      for (int g = 0; g < 4; ++g) {
        plswap(w[g*4+0], w[g*4+2]);
        plswap(w[g*4+1], w[g*4+3]);
      }
      // layer 2 (swapped): zacc[q2] = W2^T(block q2) @ z1^T, + bias kstep
      f32x16 zacc[2] = {};
      zacc[0] = __builtin_amdgcn_mfma_f32_32x32x16_f16(ab2f[0], bcst, zacc[0], 0,0,0);
      zacc[1] = __builtin_amdgcn_mfma_f32_32x32x16_f16(ab2f[1], bcst, zacc[1], 0,0,0);
#pragma unroll
      for (int t2 = 0; t2 < 4; ++t2) {
        MEMFENCE;                              // keep Wd2 frags per-step too
        H8 zf; zf.u[0] = w[4*t2]; zf.u[1] = w[4*t2+1]; zf.u[2] = w[4*t2+2]; zf.u[3] = w[4*t2+3];
        f16x8 w20 = *(const f16x8*)(w2a + ((t2*2+0)*64 + lane)*4);
        f16x8 w21 = *(const f16x8*)(w2a + ((t2*2+1)*64 + lane)*4);
        zacc[0] = __builtin_amdgcn_mfma_f32_32x32x16_f16(w20, zf.h, zacc[0], 0,0,0);
        zacc[1] = __builtin_amdgcn_mfma_f32_32x32x16_f16(w21, zf.h, zacc[1], 0,0,0);
      }
      // final: prelu(z2) . W3, lane-local over this lane's 32 d2 values + cross-half add
      float ssum = 0.f;
#pragma unroll
      for (int q2 = 0; q2 < 2; ++q2)
#pragma unroll
        for (int a = 0; a < 8; ++a) {
          f16x2 pz = pkrtz(zacc[q2][2*a], zacc[q2][2*a+1]);
          pz = __builtin_elementwise_max(pz, pz * a2v);
          ssum = fdot2a(pz, w3q[q2][a], ssum);
        }
      ssum += __shfl_xor(ssum, 32);
      int gi = I*32 + i0 + m;
      if (h2 == 0 && gi < gj && gj < NN) {
        int eo = bofs + gi*(799 - gi)/2 + (gj - gi - 1);
        out[eo] = ssum + b3;
      }
    }
  }
}

extern "C" void kernel_launch(void* const* d_in, const int* in_sizes, int n_in,
                              void* d_out, int out_size, void* d_ws, size_t ws_size,
                              hipStream_t stream) {
  const float* nf  = (const float*)d_in[1];
  const float* sc  = (const float*)d_in[2];
  const float* sm  = (const float*)d_in[3];
  const float* ss  = (const float*)d_in[4];
  const float* We1 = (const float*)d_in[5];
  const float* be1 = (const float*)d_in[6];
  const float* ae1 = (const float*)d_in[7];
  const float* We2 = (const float*)d_in[8];
  const float* be2 = (const float*)d_in[9];
  const float* ae2 = (const float*)d_in[10];
  const float* W1  = (const float*)d_in[11];
  const float* b1  = (const float*)d_in[12];
  const float* a1  = (const float*)d_in[13];
  const float* W2  = (const float*)d_in[14];
  const float* b2  = (const float*)d_in[15];
  const float* a2  = (const float*)d_in[16];
  const float* W3  = (const float*)d_in[17];
  const float* b3  = (const float*)d_in[18];
  float* out = (float*)d_out;

  char* ws = (char*)d_ws;
  float* mpart = (float*)ws;                             // 256 f32 = 1,024 B
  f16*   hbuf = (f16*)(ws + 1024);                       // 1,228,800 B
  u32*   wq   = (u32*)(ws + 1024 + 1228800);             // 143,360 B

  prep_mean_kernel<<<396, 256, 0, stream>>>(We1, We2, W1, W2, sc, wq, mpart);
  enc_kernel<<<200, 256, 0, stream>>>(sc, nf, sm, ss, be1, ae1, be2, ae2,
                                      mpart, wq, hbuf);
  decoder_kernel<<<BATCH*NPAIRS, 256, 0, stream>>>(hbuf, wq, b1, b2, a1, a2,
                                                   W3, b3, out);
}

// Round 7
// 183.261 us; speedup vs baseline: 1.0126x; 1.0126x over previous
//
#include <hip/hip_runtime.h>

#define NN 400
#define HID 96
#define EDGES 79800
#define BATCH 16
#define ROWS (BATCH*EDGES)
#define NT 13            // node tiles of 32 (tile 12 half-padded)
#define NPAIRS 91        // NT*(NT+1)/2

typedef _Float16 f16;
typedef f16 f16x2 __attribute__((ext_vector_type(2)));
typedef f16 f16x8 __attribute__((ext_vector_type(8)));
typedef __fp16 fp16x2 __attribute__((ext_vector_type(2)));
typedef float f32x16 __attribute__((ext_vector_type(16)));
typedef unsigned int u32;
typedef unsigned long long u64;

union H8 { f16x8 h; u32 u[4]; f16x2 p[4]; fp16x2 q[4]; u64 d[2]; };
union C2 { f16x2 h; fp16x2 q; u32 u; };

__device__ inline f16x2 pkrtz(float a, float b) {
  C2 c; c.q = __builtin_amdgcn_cvt_pkrtz(a, b); return c.h;
}
__device__ inline u32 pkrtz_u(float a, float b) {
  C2 c; c.q = __builtin_amdgcn_cvt_pkrtz(a, b); return c.u;
}
__device__ inline float fdot2a(f16x2 a, f16x2 b, float c) {
#if __has_builtin(__builtin_amdgcn_fdot2)
  C2 ca, cb; ca.h = a; cb.h = b;
  return __builtin_amdgcn_fdot2(ca.q, cb.q, c, false);
#else
  return c + (float)a.x*(float)b.x + (float)a.y*(float)b.y;
#endif
}

__device__ inline f16x8 habs8(f16x8 x) {
  H8 t; t.h = x;
  t.u[0] &= 0x7fff7fffu; t.u[1] &= 0x7fff7fffu;
  t.u[2] &= 0x7fff7fffu; t.u[3] &= 0x7fff7fffu;
  return t.h;
}

__device__ inline f16x8 pack8(float a0,float a1,float a2,float a3,
                              float a4,float a5,float a6,float a7){
  H8 u;
  u.p[0] = pkrtz(a0,a1);
  u.p[1] = pkrtz(a2,a3);
  u.p[2] = pkrtz(a4,a5);
  u.p[3] = pkrtz(a6,a7);
  return u.h;
}

// v_permlane32_swap_b32: vdst.hi32lanes <-> vsrc.lo32lanes.
__device__ inline void plswap(u32 &x, u32 &y) {
  auto r = __builtin_amdgcn_permlane32_swap((int)x, (int)y, false, false);
  x = (u32)r[0]; y = (u32)r[1];
}

// Aliasing fence: stops LICM/scheduler from hoisting+clustering loop-invariant LDS reads
// (the R2-R4 spill source). Register-only ops (MFMA, packs) are unaffected.
#define MEMFENCE asm volatile("" ::: "memory")

// ---------------- fused prep (blocks 0..139) + per-batch partial mean (blocks 140..395) --------
// wq regions (dwords): Wd1 [0,9216)  Wd2 plain-K [9216,11264)  We1 [11264,31232)  We2 [31232,35840)
__global__ void prep_mean_kernel(const float* __restrict__ We1, const float* __restrict__ We2,
                                 const float* __restrict__ W1, const float* __restrict__ W2,
                                 const float* __restrict__ sc,
                                 u32* __restrict__ wq, float* __restrict__ mpart) {
  if (blockIdx.x >= 140) {
    int p = blockIdx.x - 140;           // 0..255
    int b = p >> 4, part = p & 15;
    const float4* src = (const float4*)(sc + (size_t)b*160000) + part*2500;
    float s = 0.f;
    for (int i = threadIdx.x; i < 2500; i += 256) {
      float4 v = src[i];
      s += (v.x + v.y) + (v.z + v.w);
    }
    __shared__ float red[256];
    red[threadIdx.x] = s; __syncthreads();
    for (int off = 128; off > 0; off >>= 1) {
      if (threadIdx.x < off) red[threadIdx.x] += red[threadIdx.x + off];
      __syncthreads();
    }
    if (threadIdx.x == 0) mpart[p] = red[0];
    return;
  }
  int D = blockIdx.x*256 + threadIdx.x;     // 0..35839
  float v0, v1;
  if (D < 9216) {               // W_d1 frags (288 x 64), d = 32q+c  (A-frag == B-frag layout)
    int frag = D >> 8;  int t = frag >> 1, q = frag & 1;
    int rem = D & 255;  int lane = rem >> 2, dj = rem & 3;
    int c = lane & 31, h2 = lane >> 5;
    int k = 16*t + 8*h2 + 2*dj;
    int d = 32*q + c;
    v0 = W1[k*64 + d]; v1 = W1[(k+1)*64 + d];
  } else if (D < 11264) {       // W_d2 frags, PLAIN K (A-frags for swapped layer-2)
    int Dl = D - 9216;
    int frag = Dl >> 8; int t2 = frag >> 1, q = frag & 1;
    int rem = Dl & 255; int lane = rem >> 2, dj = rem & 3;
    int c = lane & 31, h2 = lane >> 5;
    int k = 16*t2 + 8*h2 + 2*dj;
    int d = 32*q + c;
    v0 = W2[k*64 + d]; v1 = W2[(k+1)*64 + d];
  } else if (D < 31232) {       // W_e1 frags (416 x 96), sc features first, static at 400
    int Dl = D - 11264;
    int frag = Dl >> 8; int t = frag/3, ct = frag - 3*t;
    int rem = Dl & 255; int lane = rem >> 2, dj = rem & 3;
    int c = lane & 31, h2 = lane >> 5;
    int k0 = 16*t + 8*h2 + 2*dj, k1 = k0 + 1;
    int d = 32*ct + c;
    v0 = (k0 < 400) ? We1[(8+k0)*96 + d] : (k0 < 408 ? We1[(k0-400)*96 + d] : 0.f);
    v1 = (k1 < 400) ? We1[(8+k1)*96 + d] : (k1 < 408 ? We1[(k1-400)*96 + d] : 0.f);
  } else {                      // W_e2 frags (96 x 96), plain K order
    int Dl = D - 31232;
    int frag = Dl >> 8; int t = frag/3, ct = frag - 3*t;
    int rem = Dl & 255; int lane = rem >> 2, dj = rem & 3;
    int c = lane & 31, h2 = lane >> 5;
    int k = 16*t + 8*h2 + 2*dj;
    int d = 32*ct + c;
    v0 = We2[k*96 + d]; v1 = We2[(k+1)*96 + d];
  }
  wq[D] = pkrtz_u(v0, v1);
}

// ---------------- fused encoder, K-split across 4 waves (R6 form, measured best) ---------------
__global__ __launch_bounds__(256) void enc_kernel(
    const float* __restrict__ sc, const float* __restrict__ nf,
    const float* __restrict__ smean, const float* __restrict__ sstd,
    const float* __restrict__ be1, const float* __restrict__ ae1,
    const float* __restrict__ be2, const float* __restrict__ ae2,
    const float* __restrict__ mpart, const u32* __restrict__ wq,
    f16* __restrict__ hout) {
  __shared__ u32 lds[12288 + 1664];
  const int tid = threadIdx.x;
  const int wid = tid >> 6, lane = tid & 63;
  const int c = lane & 31, h2 = lane >> 5;
  const int r0 = blockIdx.x * 32;
  {
    int row = tid >> 3, seg = tid & 7;
    int r = r0 + row;
    int b = r / 400;
    float ms = 0.f;
    const float4* mp4 = (const float4*)(mpart + 16*b);
#pragma unroll
    for (int k = 0; k < 4; ++k) { float4 v = mp4[k]; ms += (v.x+v.y)+(v.z+v.w); }
    float rm = 1.f / fmaxf(ms*(1.f/160000.f), 1e-8f);
    const float4* src = (const float4*)(sc + (size_t)r*400);
#pragma unroll
    for (int i = 0; i < 13; ++i) {
      int col4 = seg + 8*i;
      if (col4 < 100) {
        float4 v = src[col4];
        u32 lo = pkrtz_u(v.x*rm, v.y*rm);
        u32 hi = pkrtz_u(v.z*rm, v.w*rm);
        *(u64*)(lds + row*210 + col4*2) = (u64)lo | ((u64)hi << 32);
      }
    }
  }
  __syncthreads();
  int tb = (wid==0) ? 0 : (wid==1) ? 7 : (wid==2) ? 14 : 20;
  int te = (wid==0) ? 7 : (wid==1) ? 14 : (wid==2) ? 20 : 26;
  f32x16 acc[3] = {};
  const u32* wb1 = wq + 11264;
  for (int t = tb; t < te; ++t) {
    f16x8 af;
    if (t < 25) {
      H8 av;
      const u32* ap = lds + c*210 + 8*t + 4*h2;
      av.d[0] = *(const u64*)ap;
      av.d[1] = *(const u64*)(ap + 2);
      af = av.h;
    } else {
      af = (f16x8){};
      if (h2 == 0) {
        int r = r0 + c;
        float q0[8];
#pragma unroll
        for (int j = 0; j < 8; ++j)
          q0[j] = (nf[r*8 + j] - smean[j]) / (sstd[j] + 1e-8f);
        af = pack8(q0[0],q0[1],q0[2],q0[3],q0[4],q0[5],q0[6],q0[7]);
      }
    }
#pragma unroll
    for (int ct = 0; ct < 3; ++ct) {
      f16x8 bf = *(const f16x8*)(wb1 + ((t*3+ct)*64 + lane)*4);
      acc[ct] = __builtin_amdgcn_mfma_f32_32x32x16_f16(af, bf, acc[ct], 0,0,0);
    }
  }
  __syncthreads();
#pragma unroll
  for (int ct = 0; ct < 3; ++ct) {
    union { f32x16 v; float4 f[4]; } u; u.v = acc[ct];
#pragma unroll
    for (int i4 = 0; i4 < 4; ++i4)
      *(float4*)(lds + (((wid*3+ct)*4 + i4)*64 + lane)*4) = u.f[i4];
  }
  __syncthreads();
  f16* zb16 = (f16*)(lds + 12288);
  const float a1 = *ae1;
  if (wid < 3) {
    float bv = be1[32*wid + c];
    f32x16 s;
#pragma unroll
    for (int i = 0; i < 16; ++i) s[i] = bv;
#pragma unroll
    for (int w2 = 0; w2 < 4; ++w2) {
#pragma unroll
      for (int i4 = 0; i4 < 4; ++i4) {
        float4 f = *(const float4*)(lds + (((w2*3+wid)*4 + i4)*64 + lane)*4);
        s[4*i4+0] += f.x; s[4*i4+1] += f.y; s[4*i4+2] += f.z; s[4*i4+3] += f.w;
      }
    }
#pragma unroll
    for (int r = 0; r < 16; ++r) {
      float v = s[r]; v = fmaxf(v, a1*v);
      int row = (r & 3) + 8*(r >> 2) + 4*h2;
      zb16[row*104 + 32*wid + c] = (f16)v;
    }
  }
  __syncthreads();
  if (wid < 3) {
    const float a2 = *ae2;
    float bv = be2[32*wid + c];
    f32x16 acc2;
#pragma unroll
    for (int i = 0; i < 16; ++i) acc2[i] = bv;
    const u32* wb2 = wq + 31232;
#pragma unroll
    for (int t = 0; t < 6; ++t) {
      f16x8 af = *(const f16x8*)(zb16 + c*104 + 16*t + 8*h2);
      f16x8 bf = *(const f16x8*)(wb2 + ((t*3+wid)*64 + lane)*4);
      acc2 = __builtin_amdgcn_mfma_f32_32x32x16_f16(af, bf, acc2, 0,0,0);
    }
#pragma unroll
    for (int rr = 0; rr < 16; ++rr) {
      int row = (rr & 3) + 8*(rr >> 2) + 4*h2;
      float v = acc2[rr]; v = fmaxf(v, a2*v);
      hout[(r0 + row)*96 + 32*wid + c] = (f16)v;
    }
  }
}

// ---------------- decoder v8: (256,2) + 1-step register double-buffer pipeline ----------------
// R5 analysis: fences fixed spills but exposed the per-t lgkmcnt wait (~120cy) — MfmaUtil 40%.
// Named A/B frag sets (8 each: 6 weights + 2 hi-rows) give exactly 1-step lookahead: issue
// t+1's ds_reads BEFORE t's MFMA cluster, fence after each issue batch. Window <=16 frags,
// peak ~240 regs <= (256,2) budget. + Wd2 hoisted once per it (shared across m-pair),
// + setprio(1) around MFMA clusters (barrier-free loop -> wave phase diversity, T5 regime),
// + final reduce as two 8-deep fdot2 chains.
// LDS (dwords): hI [0,1536)  Wd1 frags [1536,10752)  Wd2 frags [10752,12800)  = 51,200 B
__global__ __launch_bounds__(256, 2) void decoder_kernel(
    const f16* __restrict__ hbuf, const u32* __restrict__ wq,
    const float* __restrict__ b1, const float* __restrict__ b2,
    const float* __restrict__ ad1, const float* __restrict__ ad2,
    const float* __restrict__ W3, const float* __restrict__ b3p,
    float* __restrict__ out) {
  __shared__ alignas(16) u32 smem[12800];
  const int tid = threadIdx.x;
  // task decode
  int p = blockIdx.x;
  int b = p / NPAIRS, pr = p - b*NPAIRS;
  int I = 0;
  while (pr >= NT - I) { pr -= NT - I; ++I; }
  const int J = I + pr;
  // stage hI rows: 32 rows x 48 dwords (clamped for tile 12)
  for (int i = tid; i < 384; i += 256) {
    int row = i / 12, off = i - row*12;
    int nb = I*32 + row; nb = nb < NN ? nb : NN-1;
    const float4* src = (const float4*)(hbuf + (size_t)(b*NN + nb)*HID) + off;
    *((float4*)(smem + row*48) + off) = *src;
  }
  // stage Wd1 (9216 dw) + Wd2 (2048 dw) contiguously
  {
    float4* dst = (float4*)(smem + 1536);
    const float4* srcw = (const float4*)wq;
    for (int i = tid; i < 2816; i += 256) dst[i] = srcw[i];
  }

  const int lane = tid & 63;
  const int wid  = tid >> 6;
  const int c = lane & 31, h2 = lane >> 5;
  const int gj = J*32 + c;
  const int gjc = gj < NN ? gj : NN-1;
  // hj frags for this lane's edge column, loop-invariant -> registers (from global, L2-hot)
  f16x8 hjr[6];
  {
    const f16* hjp = hbuf + (size_t)(b*NN + gjc)*HID + 8*h2;
#pragma unroll
    for (int t = 0; t < 6; ++t) hjr[t] = *(const f16x8*)(hjp + 16*t);
  }
  const float a1 = *ad1, a2 = *ad2, b3 = *b3p;
  const f16x2 a1v = pkrtz(a1, a1);
  const f16x2 a2v = pkrtz(a2, a2);
  // bias MFMA operands: B = const-1 frag (k-slot 0 of the extra kstep), A = bias column
  f16x8 bcst = (f16x8){};
  f16x8 ab1f[2]; ab1f[0] = (f16x8){}; ab1f[1] = (f16x8){};
  f16x8 ab2f[2]; ab2f[0] = (f16x8){}; ab2f[1] = (f16x8){};
  if (h2 == 0) {
    bcst[0] = (f16)1.f;
    ab1f[0][0] = (f16)b1[c];      ab1f[1][0] = (f16)b1[32 + c];
    ab2f[0][0] = (f16)b2[c];      ab2f[1][0] = (f16)b2[32 + c];
  }
  // W3 packed per-lane pairs matching acc row layout
  f16x2 w3q[2][8];
#pragma unroll
  for (int q2 = 0; q2 < 2; ++q2)
#pragma unroll
    for (int a = 0; a < 8; ++a) {
      int base = 32*q2 + 8*(a >> 1) + 2*(a & 1) + 4*h2;
      w3q[q2][a] = pkrtz(W3[base], W3[base + 1]);
    }
  __syncthreads();

  const f16* hIb = (const f16*)smem;
  const u32* wfr = smem + 1536;
  const u32* w2a = smem + 10752;
  const int bofs = b*EDGES;

// load one t-step's operand set into named frag set n: 6 weight frags + 2 hi-row frags
#define LDW(n, tt) \
  n##s0 = *(const f16x8*)(wfr + ((((tt)    )*2+0)*64 + lane)*4); \
  n##s1 = *(const f16x8*)(wfr + ((((tt)    )*2+1)*64 + lane)*4); \
  n##d0 = *(const f16x8*)(wfr + ((((tt)+ 6)*2+0)*64 + lane)*4); \
  n##d1 = *(const f16x8*)(wfr + ((((tt)+ 6)*2+1)*64 + lane)*4); \
  n##p0 = *(const f16x8*)(wfr + ((((tt)+12)*2+0)*64 + lane)*4); \
  n##p1 = *(const f16x8*)(wfr + ((((tt)+12)*2+1)*64 + lane)*4); \
  n##h0 = *(const f16x8*)(hi0 + 16*(tt) + 8*h2); \
  n##h1 = *(const f16x8*)(hi1 + 16*(tt) + 8*h2)

// consume frag set n for t-step tt: edge features + 12 MFMA (4 indep acc chains)
#define STEP(n, tt) { \
  f16x8 hj8 = hjr[tt]; \
  f16x8 su0 = n##h0 + hj8, di0 = habs8(n##h0 - hj8), pr0 = n##h0 * hj8; \
  f16x8 su1 = n##h1 + hj8, di1 = habs8(n##h1 - hj8), pr1 = n##h1 * hj8; \
  __builtin_amdgcn_s_setprio(1); \
  acc[0][0] = __builtin_amdgcn_mfma_f32_32x32x16_f16(n##s0, su0, acc[0][0],0,0,0); \
  acc[0][1] = __builtin_amdgcn_mfma_f32_32x32x16_f16(n##s1, su0, acc[0][1],0,0,0); \
  acc[1][0] = __builtin_amdgcn_mfma_f32_32x32x16_f16(n##s0, su1, acc[1][0],0,0,0); \
  acc[1][1] = __builtin_amdgcn_mfma_f32_32x32x16_f16(n##s1, su1, acc[1][1],0,0,0); \
  acc[0][0] = __builtin_amdgcn_mfma_f32_32x32x16_f16(n##d0, di0, acc[0][0],0,0,0); \
  acc[0][1] = __builtin_amdgcn_mfma_f32_32x32x16_f16(n##d1, di0, acc[0][1],0,0,0); \
  acc[1][0] = __builtin_amdgcn_mfma_f32_32x32x16_f16(n##d0, di1, acc[1][0],0,0,0); \
  acc[1][1] = __builtin_amdgcn_mfma_f32_32x32x16_f16(n##d1, di1, acc[1][1],0,0,0); \
  acc[0][0] = __builtin_amdgcn_mfma_f32_32x32x16_f16(n##p0, pr0, acc[0][0],0,0,0); \
  acc[0][1] = __builtin_amdgcn_mfma_f32_32x32x16_f16(n##p1, pr0, acc[0][1],0,0,0); \
  acc[1][0] = __builtin_amdgcn_mfma_f32_32x32x16_f16(n##p0, pr1, acc[1][0],0,0,0); \
  acc[1][1] = __builtin_amdgcn_mfma_f32_32x32x16_f16(n##p1, pr1, acc[1][1],0,0,0); \
  __builtin_amdgcn_s_setprio(0); }

#pragma unroll 1
  for (int it = 0; it < 4; ++it) {
    MEMFENCE;                                  // block LICM across the it-loop
    const int i0 = it*8 + wid*2;
    const f16* hi0 = hIb + (i0+0)*HID;
    const f16* hi1 = hIb + (i0+1)*HID;
    f32x16 acc[2][2] = {};
    // bias kstep first — register-only MFMAs run while the prologue loads fly
    acc[0][0] = __builtin_amdgcn_mfma_f32_32x32x16_f16(ab1f[0], bcst, acc[0][0], 0,0,0);
    acc[0][1] = __builtin_amdgcn_mfma_f32_32x32x16_f16(ab1f[1], bcst, acc[0][1], 0,0,0);
    acc[1][0] = __builtin_amdgcn_mfma_f32_32x32x16_f16(ab1f[0], bcst, acc[1][0], 0,0,0);
    acc[1][1] = __builtin_amdgcn_mfma_f32_32x32x16_f16(ab1f[1], bcst, acc[1][1], 0,0,0);
    // layer 1: K=288, software-pipelined 1-deep: issue t+1 loads before t's MFMA cluster
    f16x8 As0,As1,Ad0,Ad1,Ap0,Ap1,Ah0,Ah1;
    f16x8 Bs0,Bs1,Bd0,Bd1,Bp0,Bp1,Bh0,Bh1;
    LDW(A, 0); MEMFENCE;
    LDW(B, 1); MEMFENCE; STEP(A, 0);
    LDW(A, 2); MEMFENCE; STEP(B, 1);
    LDW(B, 3); MEMFENCE; STEP(A, 2);
    LDW(A, 4); MEMFENCE; STEP(B, 3);
    LDW(B, 5); MEMFENCE; STEP(A, 4);
    STEP(B, 5);
    // hoist all 8 Wd2 frags once per it (shared across the m-pair)
    MEMFENCE;
    f16x8 w2r[4][2];
#pragma unroll
    for (int t2 = 0; t2 < 4; ++t2) {
      w2r[t2][0] = *(const f16x8*)(w2a + ((t2*2+0)*64 + lane)*4);
      w2r[t2][1] = *(const f16x8*)(w2a + ((t2*2+1)*64 + lane)*4);
    }
    MEMFENCE;
#pragma unroll
    for (int m = 0; m < 2; ++m) {
      // pack + packed-prelu the 32 z1 values, then permlane-swap h2 halves -> layer-2 B-frags
      u32 w[16];
#pragma unroll
      for (int q = 0; q < 2; ++q)
#pragma unroll
        for (int a = 0; a < 8; ++a) {
          f16x2 pz = pkrtz(acc[m][q][2*a], acc[m][q][2*a+1]);
          pz = __builtin_elementwise_max(pz, pz * a1v);
          C2 cv; cv.h = pz; w[q*8 + a] = cv.u;
        }
#pragma unroll
      for (int g = 0; g < 4; ++g) {
        plswap(w[g*4+0], w[g*4+2]);
        plswap(w[g*4+1], w[g*4+3]);
      }
      // layer 2 (swapped): zacc[q2] = W2^T(block q2) @ z1^T, + bias kstep
      f32x16 zacc[2] = {};
      zacc[0] = __builtin_amdgcn_mfma_f32_32x32x16_f16(ab2f[0], bcst, zacc[0], 0,0,0);
      zacc[1] = __builtin_amdgcn_mfma_f32_32x32x16_f16(ab2f[1], bcst, zacc[1], 0,0,0);
      __builtin_amdgcn_s_setprio(1);
#pragma unroll
      for (int t2 = 0; t2 < 4; ++t2) {
        H8 zf; zf.u[0] = w[4*t2]; zf.u[1] = w[4*t2+1]; zf.u[2] = w[4*t2+2]; zf.u[3] = w[4*t2+3];
        zacc[0] = __builtin_amdgcn_mfma_f32_32x32x16_f16(w2r[t2][0], zf.h, zacc[0], 0,0,0);
        zacc[1] = __builtin_amdgcn_mfma_f32_32x32x16_f16(w2r[t2][1], zf.h, zacc[1], 0,0,0);
      }
      __builtin_amdgcn_s_setprio(0);
      // final: prelu(z2) . W3 — two independent 8-deep fdot2 chains + cross-half add
      float s0 = 0.f, s1 = 0.f;
#pragma unroll
      for (int a = 0; a < 8; ++a) {
        f16x2 pz0 = pkrtz(zacc[0][2*a], zacc[0][2*a+1]);
        pz0 = __builtin_elementwise_max(pz0, pz0 * a2v);
        s0 = fdot2a(pz0, w3q[0][a], s0);
        f16x2 pz1 = pkrtz(zacc[1][2*a], zacc[1][2*a+1]);
        pz1 = __builtin_elementwise_max(pz1, pz1 * a2v);
        s1 = fdot2a(pz1, w3q[1][a], s1);
      }
      float ssum = s0 + s1;
      ssum += __shfl_xor(ssum, 32);
      int gi = I*32 + i0 + m;
      if (h2 == 0 && gi < gj && gj < NN) {
        int eo = bofs + gi*(799 - gi)/2 + (gj - gi - 1);
        out[eo] = ssum + b3;
      }
    }
  }
#undef LDW
#undef STEP
}

extern "C" void kernel_launch(void* const* d_in, const int* in_sizes, int n_in,
                              void* d_out, int out_size, void* d_ws, size_t ws_size,
                              hipStream_t stream) {
  const float* nf  = (const float*)d_in[1];
  const float* sc  = (const float*)d_in[2];
  const float* sm  = (const float*)d_in[3];
  const float* ss  = (const float*)d_in[4];
  const float* We1 = (const float*)d_in[5];
  const float* be1 = (const float*)d_in[6];
  const float* ae1 = (const float*)d_in[7];
  const float* We2 = (const float*)d_in[8];
  const float* be2 = (const float*)d_in[9];
  const float* ae2 = (const float*)d_in[10];
  const float* W1  = (const float*)d_in[11];
  const float* b1  = (const float*)d_in[12];
  const float* a1  = (const float*)d_in[13];
  const float* W2  = (const float*)d_in[14];
  const float* b2  = (const float*)d_in[15];
  const float* a2  = (const float*)d_in[16];
  const float* W3  = (const float*)d_in[17];
  const float* b3  = (const float*)d_in[18];
  float* out = (float*)d_out;

  char* ws = (char*)d_ws;
  float* mpart = (float*)ws;                             // 256 f32 = 1,024 B
  f16*   hbuf = (f16*)(ws + 1024);                       // 1,228,800 B
  u32*   wq   = (u32*)(ws + 1024 + 1228800);             // 143,360 B

  prep_mean_kernel<<<396, 256, 0, stream>>>(We1, We2, W1, W2, sc, wq, mpart);
  enc_kernel<<<200, 256, 0, stream>>>(sc, nf, sm, ss, be1, ae1, be2, ae2,
                                      mpart, wq, hbuf);
  decoder_kernel<<<BATCH*NPAIRS, 256, 0, stream>>>(hbuf, wq, b1, b2, a1, a2,
                                                   W3, b3, out);
}

// Round 9
// 178.830 us; speedup vs baseline: 1.0377x; 1.0248x over previous
//
#include <hip/hip_runtime.h>

#define NN 400
#define HID 96
#define EDGES 79800
#define BATCH 16
#define ROWS (BATCH*EDGES)
#define NT 13            // node tiles of 32 (tile 12 half-padded)
#define NPAIRS 91        // NT*(NT+1)/2

typedef _Float16 f16;
typedef f16 f16x2 __attribute__((ext_vector_type(2)));
typedef f16 f16x8 __attribute__((ext_vector_type(8)));
typedef __fp16 fp16x2 __attribute__((ext_vector_type(2)));
typedef float f32x16 __attribute__((ext_vector_type(16)));
typedef unsigned int u32;
typedef unsigned long long u64;

union H8 { f16x8 h; u32 u[4]; f16x2 p[4]; fp16x2 q[4]; u64 d[2]; };
union C2 { f16x2 h; fp16x2 q; u32 u; };

__device__ inline f16x2 pkrtz(float a, float b) {
  C2 c; c.q = __builtin_amdgcn_cvt_pkrtz(a, b); return c.h;
}
__device__ inline u32 pkrtz_u(float a, float b) {
  C2 c; c.q = __builtin_amdgcn_cvt_pkrtz(a, b); return c.u;
}
__device__ inline float fdot2a(f16x2 a, f16x2 b, float c) {
#if __has_builtin(__builtin_amdgcn_fdot2)
  C2 ca, cb; ca.h = a; cb.h = b;
  return __builtin_amdgcn_fdot2(ca.q, cb.q, c, false);
#else
  return c + (float)a.x*(float)b.x + (float)a.y*(float)b.y;
#endif
}

__device__ inline f16x8 habs8(f16x8 x) {
  H8 t; t.h = x;
  t.u[0] &= 0x7fff7fffu; t.u[1] &= 0x7fff7fffu;
  t.u[2] &= 0x7fff7fffu; t.u[3] &= 0x7fff7fffu;
  return t.h;
}

__device__ inline f16x8 pack8(float a0,float a1,float a2,float a3,
                              float a4,float a5,float a6,float a7){
  H8 u;
  u.p[0] = pkrtz(a0,a1);
  u.p[1] = pkrtz(a2,a3);
  u.p[2] = pkrtz(a4,a5);
  u.p[3] = pkrtz(a6,a7);
  return u.h;
}

// v_permlane32_swap_b32: vdst.hi32lanes <-> vsrc.lo32lanes.
__device__ inline void plswap(u32 &x, u32 &y) {
  auto r = __builtin_amdgcn_permlane32_swap((int)x, (int)y, false, false);
  x = (u32)r[0]; y = (u32)r[1];
}

// Aliasing fence: stops LICM/scheduler from hoisting+clustering loop-invariant LDS reads
// (the R2-R4 spill source). Register-only ops (MFMA, packs) are unaffected.
#define MEMFENCE asm volatile("" ::: "memory")

// ---------------- fused prep (blocks 0..139) + per-batch partial mean (blocks 140..395) --------
// wq regions (dwords): Wd1 [0,9216)  Wd2 plain-K [9216,11264)  We1 [11264,31232)  We2 [31232,35840)
__global__ void prep_mean_kernel(const float* __restrict__ We1, const float* __restrict__ We2,
                                 const float* __restrict__ W1, const float* __restrict__ W2,
                                 const float* __restrict__ sc,
                                 u32* __restrict__ wq, float* __restrict__ mpart) {
  if (blockIdx.x >= 140) {
    int p = blockIdx.x - 140;           // 0..255
    int b = p >> 4, part = p & 15;
    const float4* src = (const float4*)(sc + (size_t)b*160000) + part*2500;
    float s = 0.f;
    for (int i = threadIdx.x; i < 2500; i += 256) {
      float4 v = src[i];
      s += (v.x + v.y) + (v.z + v.w);
    }
    __shared__ float red[256];
    red[threadIdx.x] = s; __syncthreads();
    for (int off = 128; off > 0; off >>= 1) {
      if (threadIdx.x < off) red[threadIdx.x] += red[threadIdx.x + off];
      __syncthreads();
    }
    if (threadIdx.x == 0) mpart[p] = red[0];
    return;
  }
  int D = blockIdx.x*256 + threadIdx.x;     // 0..35839
  float v0, v1;
  if (D < 9216) {               // W_d1 frags (288 x 64), d = 32q+c  (A-frag == B-frag layout)
    int frag = D >> 8;  int t = frag >> 1, q = frag & 1;
    int rem = D & 255;  int lane = rem >> 2, dj = rem & 3;
    int c = lane & 31, h2 = lane >> 5;
    int k = 16*t + 8*h2 + 2*dj;
    int d = 32*q + c;
    v0 = W1[k*64 + d]; v1 = W1[(k+1)*64 + d];
  } else if (D < 11264) {       // W_d2 frags, PLAIN K (A-frags for swapped layer-2)
    int Dl = D - 9216;
    int frag = Dl >> 8; int t2 = frag >> 1, q = frag & 1;
    int rem = Dl & 255; int lane = rem >> 2, dj = rem & 3;
    int c = lane & 31, h2 = lane >> 5;
    int k = 16*t2 + 8*h2 + 2*dj;
    int d = 32*q + c;
    v0 = W2[k*64 + d]; v1 = W2[(k+1)*64 + d];
  } else if (D < 31232) {       // W_e1 frags (416 x 96), sc features first, static at 400
    int Dl = D - 11264;
    int frag = Dl >> 8; int t = frag/3, ct = frag - 3*t;
    int rem = Dl & 255; int lane = rem >> 2, dj = rem & 3;
    int c = lane & 31, h2 = lane >> 5;
    int k0 = 16*t + 8*h2 + 2*dj, k1 = k0 + 1;
    int d = 32*ct + c;
    v0 = (k0 < 400) ? We1[(8+k0)*96 + d] : (k0 < 408 ? We1[(k0-400)*96 + d] : 0.f);
    v1 = (k1 < 400) ? We1[(8+k1)*96 + d] : (k1 < 408 ? We1[(k1-400)*96 + d] : 0.f);
  } else {                      // W_e2 frags (96 x 96), plain K order
    int Dl = D - 31232;
    int frag = Dl >> 8; int t = frag/3, ct = frag - 3*t;
    int rem = Dl & 255; int lane = rem >> 2, dj = rem & 3;
    int c = lane & 31, h2 = lane >> 5;
    int k = 16*t + 8*h2 + 2*dj;
    int d = 32*ct + c;
    v0 = We2[k*96 + d]; v1 = We2[(k+1)*96 + d];
  }
  wq[D] = pkrtz_u(v0, v1);
}

// ---------------- encoder v2: per-wave full-K, 2 barriers, zero combine ----------------
// Old enc: 1 wave/SIMD (grid 200 < 256 CUs), 4 barriers, K-split acc-combine via 8-way
// bank-conflicted float4 LDS roundtrip, layer-2 A-reads 8-way conflicted (stride 104).
// v2: wave ct=wid owns one 32-col output tile over ALL 26 K-steps. All 26 We1 frags +
// 6 We2 frags preloaded from global BEFORE barrier 1 (overlaps sc staging latency, one
// vm wait). zb16 stride 100 f16 (50 dw, gcd(50,32)=2 -> ~2-way, free). Critical path:
// stage || preload -> bar -> 26x(ds+MFMA) -> pack -> bar -> 6x(ds+MFMA) -> store.
// LDS (dwords): staging 32x210 = 6720, zb16 32x100 f16 = 1600 -> 33,280 B.
__global__ __launch_bounds__(256) void enc_kernel(
    const float* __restrict__ sc, const float* __restrict__ nf,
    const float* __restrict__ smean, const float* __restrict__ sstd,
    const float* __restrict__ be1, const float* __restrict__ ae1,
    const float* __restrict__ be2, const float* __restrict__ ae2,
    const float* __restrict__ mpart, const u32* __restrict__ wq,
    f16* __restrict__ hout) {
  __shared__ u32 lds[6720 + 1600];
  const int tid = threadIdx.x;
  const int wid = tid >> 6, lane = tid & 63;
  const int c = lane & 31, h2 = lane >> 5;
  const int r0 = blockIdx.x * 32;
  // Phase A: stage normalized sc rows as f16 (all waves)
  {
    int row = tid >> 3, seg = tid & 7;
    int r = r0 + row;
    int b = r / 400;
    float ms = 0.f;
    const float4* mp4 = (const float4*)(mpart + 16*b);
#pragma unroll
    for (int k = 0; k < 4; ++k) { float4 v = mp4[k]; ms += (v.x+v.y)+(v.z+v.w); }
    float rm = 1.f / fmaxf(ms*(1.f/160000.f), 1e-8f);
    const float4* src = (const float4*)(sc + (size_t)r*400);
#pragma unroll
    for (int i = 0; i < 13; ++i) {
      int col4 = seg + 8*i;
      if (col4 < 100) {
        float4 v = src[col4];
        u32 lo = pkrtz_u(v.x*rm, v.y*rm);
        u32 hi = pkrtz_u(v.z*rm, v.w*rm);
        *(u64*)(lds + row*210 + col4*2) = (u64)lo | ((u64)hi << 32);
      }
    }
  }
  // weight preload (per-wave ct) + static-feature frag: independent of LDS staging,
  // issued before the barrier so the global latency hides under staging.
  f16x8 bfr[26], we2r[6], af25;
  if (wid < 3) {
    const u32* wb1 = wq + 11264;
#pragma unroll
    for (int t = 0; t < 26; ++t)
      bfr[t] = *(const f16x8*)(wb1 + ((t*3+wid)*64 + lane)*4);
    const u32* wb2 = wq + 31232;
#pragma unroll
    for (int t = 0; t < 6; ++t)
      we2r[t] = *(const f16x8*)(wb2 + ((t*3+wid)*64 + lane)*4);
    af25 = (f16x8){};
    if (h2 == 0) {
      int r = r0 + c;
      float q0[8];
#pragma unroll
      for (int j = 0; j < 8; ++j)
        q0[j] = (nf[r*8 + j] - smean[j]) / (sstd[j] + 1e-8f);
      af25 = pack8(q0[0],q0[1],q0[2],q0[3],q0[4],q0[5],q0[6],q0[7]);
    }
  }
  __syncthreads();
  f16* zb16 = (f16*)(lds + 6720);
  if (wid < 3) {
    const float a1 = *ae1;
    float bv = be1[32*wid + c];
    f32x16 acc;
#pragma unroll
    for (int i = 0; i < 16; ++i) acc[i] = bv;
#pragma unroll
    for (int t = 0; t < 25; ++t) {
      H8 av;
      const u32* ap = lds + c*210 + 8*t + 4*h2;
      av.d[0] = *(const u64*)ap;
      av.d[1] = *(const u64*)(ap + 2);
      acc = __builtin_amdgcn_mfma_f32_32x32x16_f16(av.h, bfr[t], acc, 0,0,0);
    }
    acc = __builtin_amdgcn_mfma_f32_32x32x16_f16(af25, bfr[25], acc, 0,0,0);
#pragma unroll
    for (int r = 0; r < 16; ++r) {
      float v = acc[r]; v = fmaxf(v, a1*v);
      int row = (r & 3) + 8*(r >> 2) + 4*h2;
      zb16[row*100 + 32*wid + c] = (f16)v;
    }
  }
  __syncthreads();
  if (wid < 3) {
    const float a2 = *ae2;
    float bv = be2[32*wid + c];
    f32x16 acc2;
#pragma unroll
    for (int i = 0; i < 16; ++i) acc2[i] = bv;
#pragma unroll
    for (int t = 0; t < 6; ++t) {
      f16x8 af = *(const f16x8*)(zb16 + c*100 + 16*t + 8*h2);
      acc2 = __builtin_amdgcn_mfma_f32_32x32x16_f16(af, we2r[t], acc2, 0,0,0);
    }
#pragma unroll
    for (int rr = 0; rr < 16; ++rr) {
      int row = (rr & 3) + 8*(rr >> 2) + 4*h2;
      float v = acc2[rr]; v = fmaxf(v, a2*v);
      hout[(r0 + row)*96 + 32*wid + c] = (f16)v;
    }
  }
}

// ---------------- decoder v8: (256,2) + 1-step register double-buffer pipeline ----------------
// Stable at ~77 µs, no spill (FETCH 4.7 MB), VGPR 112. Kept byte-identical to R7.
// LDS (dwords): hI [0,1536)  Wd1 frags [1536,10752)  Wd2 frags [10752,12800)  = 51,200 B
__global__ __launch_bounds__(256, 2) void decoder_kernel(
    const f16* __restrict__ hbuf, const u32* __restrict__ wq,
    const float* __restrict__ b1, const float* __restrict__ b2,
    const float* __restrict__ ad1, const float* __restrict__ ad2,
    const float* __restrict__ W3, const float* __restrict__ b3p,
    float* __restrict__ out) {
  __shared__ alignas(16) u32 smem[12800];
  const int tid = threadIdx.x;
  // task decode
  int p = blockIdx.x;
  int b = p / NPAIRS, pr = p - b*NPAIRS;
  int I = 0;
  while (pr >= NT - I) { pr -= NT - I; ++I; }
  const int J = I + pr;
  // stage hI rows: 32 rows x 48 dwords (clamped for tile 12)
  for (int i = tid; i < 384; i += 256) {
    int row = i / 12, off = i - row*12;
    int nb = I*32 + row; nb = nb < NN ? nb : NN-1;
    const float4* src = (const float4*)(hbuf + (size_t)(b*NN + nb)*HID) + off;
    *((float4*)(smem + row*48) + off) = *src;
  }
  // stage Wd1 (9216 dw) + Wd2 (2048 dw) contiguously
  {
    float4* dst = (float4*)(smem + 1536);
    const float4* srcw = (const float4*)wq;
    for (int i = tid; i < 2816; i += 256) dst[i] = srcw[i];
  }

  const int lane = tid & 63;
  const int wid  = tid >> 6;
  const int c = lane & 31, h2 = lane >> 5;
  const int gj = J*32 + c;
  const int gjc = gj < NN ? gj : NN-1;
  // hj frags for this lane's edge column, loop-invariant -> registers (from global, L2-hot)
  f16x8 hjr[6];
  {
    const f16* hjp = hbuf + (size_t)(b*NN + gjc)*HID + 8*h2;
#pragma unroll
    for (int t = 0; t < 6; ++t) hjr[t] = *(const f16x8*)(hjp + 16*t);
  }
  const float a1 = *ad1, a2 = *ad2, b3 = *b3p;
  const f16x2 a1v = pkrtz(a1, a1);
  const f16x2 a2v = pkrtz(a2, a2);
  // bias MFMA operands: B = const-1 frag (k-slot 0 of the extra kstep), A = bias column
  f16x8 bcst = (f16x8){};
  f16x8 ab1f[2]; ab1f[0] = (f16x8){}; ab1f[1] = (f16x8){};
  f16x8 ab2f[2]; ab2f[0] = (f16x8){}; ab2f[1] = (f16x8){};
  if (h2 == 0) {
    bcst[0] = (f16)1.f;
    ab1f[0][0] = (f16)b1[c];      ab1f[1][0] = (f16)b1[32 + c];
    ab2f[0][0] = (f16)b2[c];      ab2f[1][0] = (f16)b2[32 + c];
  }
  // W3 packed per-lane pairs matching acc row layout
  f16x2 w3q[2][8];
#pragma unroll
  for (int q2 = 0; q2 < 2; ++q2)
#pragma unroll
    for (int a = 0; a < 8; ++a) {
      int base = 32*q2 + 8*(a >> 1) + 2*(a & 1) + 4*h2;
      w3q[q2][a] = pkrtz(W3[base], W3[base + 1]);
    }
  __syncthreads();

  const f16* hIb = (const f16*)smem;
  const u32* wfr = smem + 1536;
  const u32* w2a = smem + 10752;
  const int bofs = b*EDGES;

// load one t-step's operand set into named frag set n: 6 weight frags + 2 hi-row frags
#define LDW(n, tt) \
  n##s0 = *(const f16x8*)(wfr + ((((tt)    )*2+0)*64 + lane)*4); \
  n##s1 = *(const f16x8*)(wfr + ((((tt)    )*2+1)*64 + lane)*4); \
  n##d0 = *(const f16x8*)(wfr + ((((tt)+ 6)*2+0)*64 + lane)*4); \
  n##d1 = *(const f16x8*)(wfr + ((((tt)+ 6)*2+1)*64 + lane)*4); \
  n##p0 = *(const f16x8*)(wfr + ((((tt)+12)*2+0)*64 + lane)*4); \
  n##p1 = *(const f16x8*)(wfr + ((((tt)+12)*2+1)*64 + lane)*4); \
  n##h0 = *(const f16x8*)(hi0 + 16*(tt) + 8*h2); \
  n##h1 = *(const f16x8*)(hi1 + 16*(tt) + 8*h2)

// consume frag set n for t-step tt: edge features + 12 MFMA (4 indep acc chains)
#define STEP(n, tt) { \
  f16x8 hj8 = hjr[tt]; \
  f16x8 su0 = n##h0 + hj8, di0 = habs8(n##h0 - hj8), pr0 = n##h0 * hj8; \
  f16x8 su1 = n##h1 + hj8, di1 = habs8(n##h1 - hj8), pr1 = n##h1 * hj8; \
  __builtin_amdgcn_s_setprio(1); \
  acc[0][0] = __builtin_amdgcn_mfma_f32_32x32x16_f16(n##s0, su0, acc[0][0],0,0,0); \
  acc[0][1] = __builtin_amdgcn_mfma_f32_32x32x16_f16(n##s1, su0, acc[0][1],0,0,0); \
  acc[1][0] = __builtin_amdgcn_mfma_f32_32x32x16_f16(n##s0, su1, acc[1][0],0,0,0); \
  acc[1][1] = __builtin_amdgcn_mfma_f32_32x32x16_f16(n##s1, su1, acc[1][1],0,0,0); \
  acc[0][0] = __builtin_amdgcn_mfma_f32_32x32x16_f16(n##d0, di0, acc[0][0],0,0,0); \
  acc[0][1] = __builtin_amdgcn_mfma_f32_32x32x16_f16(n##d1, di0, acc[0][1],0,0,0); \
  acc[1][0] = __builtin_amdgcn_mfma_f32_32x32x16_f16(n##d0, di1, acc[1][0],0,0,0); \
  acc[1][1] = __builtin_amdgcn_mfma_f32_32x32x16_f16(n##d1, di1, acc[1][1],0,0,0); \
  acc[0][0] = __builtin_amdgcn_mfma_f32_32x32x16_f16(n##p0, pr0, acc[0][0],0,0,0); \
  acc[0][1] = __builtin_amdgcn_mfma_f32_32x32x16_f16(n##p1, pr0, acc[0][1],0,0,0); \
  acc[1][0] = __builtin_amdgcn_mfma_f32_32x32x16_f16(n##p0, pr1, acc[1][0],0,0,0); \
  acc[1][1] = __builtin_amdgcn_mfma_f32_32x32x16_f16(n##p1, pr1, acc[1][1],0,0,0); \
  __builtin_amdgcn_s_setprio(0); }

#pragma unroll 1
  for (int it = 0; it < 4; ++it) {
    MEMFENCE;                                  // block LICM across the it-loop
    const int i0 = it*8 + wid*2;
    const f16* hi0 = hIb + (i0+0)*HID;
    const f16* hi1 = hIb + (i0+1)*HID;
    f32x16 acc[2][2] = {};
    // bias kstep first — register-only MFMAs run while the prologue loads fly
    acc[0][0] = __builtin_amdgcn_mfma_f32_32x32x16_f16(ab1f[0], bcst, acc[0][0], 0,0,0);
    acc[0][1] = __builtin_amdgcn_mfma_f32_32x32x16_f16(ab1f[1], bcst, acc[0][1], 0,0,0);
    acc[1][0] = __builtin_amdgcn_mfma_f32_32x32x16_f16(ab1f[0], bcst, acc[1][0], 0,0,0);
    acc[1][1] = __builtin_amdgcn_mfma_f32_32x32x16_f16(ab1f[1], bcst, acc[1][1], 0,0,0);
    // layer 1: K=288, software-pipelined 1-deep: issue t+1 loads before t's MFMA cluster
    f16x8 As0,As1,Ad0,Ad1,Ap0,Ap1,Ah0,Ah1;
    f16x8 Bs0,Bs1,Bd0,Bd1,Bp0,Bp1,Bh0,Bh1;
    LDW(A, 0); MEMFENCE;
    LDW(B, 1); MEMFENCE; STEP(A, 0);
    LDW(A, 2); MEMFENCE; STEP(B, 1);
    LDW(B, 3); MEMFENCE; STEP(A, 2);
    LDW(A, 4); MEMFENCE; STEP(B, 3);
    LDW(B, 5); MEMFENCE; STEP(A, 4);
    STEP(B, 5);
    // hoist all 8 Wd2 frags once per it (shared across the m-pair)
    MEMFENCE;
    f16x8 w2r[4][2];
#pragma unroll
    for (int t2 = 0; t2 < 4; ++t2) {
      w2r[t2][0] = *(const f16x8*)(w2a + ((t2*2+0)*64 + lane)*4);
      w2r[t2][1] = *(const f16x8*)(w2a + ((t2*2+1)*64 + lane)*4);
    }
    MEMFENCE;
#pragma unroll
    for (int m = 0; m < 2; ++m) {
      // pack + packed-prelu the 32 z1 values, then permlane-swap h2 halves -> layer-2 B-frags
      u32 w[16];
#pragma unroll
      for (int q = 0; q < 2; ++q)
#pragma unroll
        for (int a = 0; a < 8; ++a) {
          f16x2 pz = pkrtz(acc[m][q][2*a], acc[m][q][2*a+1]);
          pz = __builtin_elementwise_max(pz, pz * a1v);
          C2 cv; cv.h = pz; w[q*8 + a] = cv.u;
        }
#pragma unroll
      for (int g = 0; g < 4; ++g) {
        plswap(w[g*4+0], w[g*4+2]);
        plswap(w[g*4+1], w[g*4+3]);
      }
      // layer 2 (swapped): zacc[q2] = W2^T(block q2) @ z1^T, + bias kstep
      f32x16 zacc[2] = {};
      zacc[0] = __builtin_amdgcn_mfma_f32_32x32x16_f16(ab2f[0], bcst, zacc[0], 0,0,0);
      zacc[1] = __builtin_amdgcn_mfma_f32_32x32x16_f16(ab2f[1], bcst, zacc[1], 0,0,0);
      __builtin_amdgcn_s_setprio(1);
#pragma unroll
      for (int t2 = 0; t2 < 4; ++t2) {
        H8 zf; zf.u[0] = w[4*t2]; zf.u[1] = w[4*t2+1]; zf.u[2] = w[4*t2+2]; zf.u[3] = w[4*t2+3];
        zacc[0] = __builtin_amdgcn_mfma_f32_32x32x16_f16(w2r[t2][0], zf.h, zacc[0], 0,0,0);
        zacc[1] = __builtin_amdgcn_mfma_f32_32x32x16_f16(w2r[t2][1], zf.h, zacc[1], 0,0,0);
      }
      __builtin_amdgcn_s_setprio(0);
      // final: prelu(z2) . W3 — two independent 8-deep fdot2 chains + cross-half add
      float s0 = 0.f, s1 = 0.f;
#pragma unroll
      for (int a = 0; a < 8; ++a) {
        f16x2 pz0 = pkrtz(zacc[0][2*a], zacc[0][2*a+1]);
        pz0 = __builtin_elementwise_max(pz0, pz0 * a2v);
        s0 = fdot2a(pz0, w3q[0][a], s0);
        f16x2 pz1 = pkrtz(zacc[1][2*a], zacc[1][2*a+1]);
        pz1 = __builtin_elementwise_max(pz1, pz1 * a2v);
        s1 = fdot2a(pz1, w3q[1][a], s1);
      }
      float ssum = s0 + s1;
      ssum += __shfl_xor(ssum, 32);
      int gi = I*32 + i0 + m;
      if (h2 == 0 && gi < gj && gj < NN) {
        int eo = bofs + gi*(799 - gi)/2 + (gj - gi - 1);
        out[eo] = ssum + b3;
      }
    }
  }
#undef LDW
#undef STEP
}

extern "C" void kernel_launch(void* const* d_in, const int* in_sizes, int n_in,
                              void* d_out, int out_size, void* d_ws, size_t ws_size,
                              hipStream_t stream) {
  const float* nf  = (const float*)d_in[1];
  const float* sc  = (const float*)d_in[2];
  const float* sm  = (const float*)d_in[3];
  const float* ss  = (const float*)d_in[4];
  const float* We1 = (const float*)d_in[5];
  const float* be1 = (const float*)d_in[6];
  const float* ae1 = (const float*)d_in[7];
  const float* We2 = (const float*)d_in[8];
  const float* be2 = (const float*)d_in[9];
  const float* ae2 = (const float*)d_in[10];
  const float* W1  = (const float*)d_in[11];
  const float* b1  = (const float*)d_in[12];
  const float* a1  = (const float*)d_in[13];
  const float* W2  = (const float*)d_in[14];
  const float* b2  = (const float*)d_in[15];
  const float* a2  = (const float*)d_in[16];
  const float* W3  = (const float*)d_in[17];
  const float* b3  = (const float*)d_in[18];
  float* out = (float*)d_out;

  char* ws = (char*)d_ws;
  float* mpart = (float*)ws;                             // 256 f32 = 1,024 B
  f16*   hbuf = (f16*)(ws + 1024);                       // 1,228,800 B
  u32*   wq   = (u32*)(ws + 1024 + 1228800);             // 143,360 B

  prep_mean_kernel<<<396, 256, 0, stream>>>(We1, We2, W1, W2, sc, wq, mpart);
  enc_kernel<<<200, 256, 0, stream>>>(sc, nf, sm, ss, be1, ae1, be2, ae2,
                                      mpart, wq, hbuf);
  decoder_kernel<<<BATCH*NPAIRS, 256, 0, stream>>>(hbuf, wq, b1, b2, a1, a2,
                                                   W3, b3, out);
}